// Round 3
// baseline (412.742 us; speedup 1.0000x reference)
//
#include <hip/hip_runtime.h>
#include <hip/hip_fp16.h>
#include <math.h>

#define B_ROWS 131072
#define NMODS 6
#define NPREDS 30

// acc layout in d_ws:
// 0 ade6x, 1 ade6y, 2 fde6x, 3 fde6y, 4 ade1x, 5 ade1y, 6 fde1x, 7 fde1y,
// 8 regloss, 9 summgn, 10 numcls, 11 numreg

__device__ __forceinline__ float wave_reduce(float v) {
    v += __shfl_xor(v, 32);
    v += __shfl_xor(v, 16);
    v += __shfl_xor(v, 8);
    v += __shfl_xor(v, 4);
    v += __shfl_xor(v, 2);
    v += __shfl_xor(v, 1);
    return v;
}

__global__ __launch_bounds__(256) void loss_lane(
    const float* __restrict__ reg,   // [B,6,30,2]
    const float* __restrict__ cls,   // [B,6]
    const float* __restrict__ gt,    // [B,30,2]
    const int* __restrict__ has,     // [B,30] bool->int32
    float* __restrict__ acc)
{
    const int r = blockIdx.x * 256 + threadIdx.x;   // one row per thread, grid exact

    // ---------------- has -> bitmask ----------------
    const int2* h2 = (const int2*)(has + (size_t)r * NPREDS);
    unsigned mask = 0u;
    #pragma unroll
    for (int i = 0; i < 15; ++i) {
        int2 h = h2[i];
        mask |= (h.x != 0 ? 1u : 0u) << (2 * i);
        mask |= (h.y != 0 ? 1u : 0u) << (2 * i + 1);
    }
    const int  last_idx = mask ? (31 - __builtin_clz(mask)) : (NPREDS - 1);
    const bool valid    = (mask & ~1u) != 0u;   // max(has + 0.1*t/30) > 1.0

    // ---------------- gt pass: moving, heading, pack to half2 regs ----------------
    const float2* grow = (const float2*)(gt + (size_t)r * NPREDS * 2);
    float2 g0  = grow[0];
    float2 g29 = grow[NPREDS - 1];
    float mdx = g0.x - g29.x, mdy = g0.y - g29.y;
    const bool moving = (mdx * mdx + mdy * mdy) > 4.0f;

    __half2 gxy[NPREDS];    // packed (gx, gy) per t
    __half2 ctst[NPREDS];   // packed (cos(-head), sin(-head)) per t

    float cx = g0.x, cy = g0.y;   // gt[t]
    float seg_prev = 0.f;         // seg[t-1]
    #pragma unroll
    for (int t = 0; t < NPREDS; ++t) {
        float nx = cx, ny = cy;
        if (t < NPREDS - 1) { float2 gn = grow[t + 1]; nx = gn.x; ny = gn.y; }
        gxy[t] = __floats2half2_rn(cx, cy);

        float head;
        if (t == 0) {
            float seg = atan2f(ny - cy, nx - cx);
            head = seg;
            seg_prev = seg;
        } else if (t < NPREDS - 1) {
            float seg = atan2f(ny - cy, nx - cx);
            head = (seg == 0.f || seg_prev == 0.f) ? (seg + seg_prev)
                                                   : 0.5f * (seg + seg_prev);
            seg_prev = seg;
        } else {
            head = seg_prev;   // head[29] = seg[28]
        }
        if (!moving) head = 0.f;
        float th = -head;
        ctst[t] = __floats2half2_rn(__cosf(th), __sinf(th));
        cx = nx; cy = ny;
    }

    // ---------------- per-mode dist at last_idx -> mini ----------------
    float2 gl = grow[last_idx];   // fp32 gt at last valid step
    const float2* rbase = (const float2*)(reg + (size_t)r * NMODS * NPREDS * 2);
    float dists[NMODS];
    #pragma unroll
    for (int m = 0; m < NMODS; ++m) {
        float2 rl = rbase[m * NPREDS + last_idx];
        float ddx = rl.x - gl.x, ddy = rl.y - gl.y;
        dists[m] = sqrtf(ddx * ddx + ddy * ddy);
    }
    float mind = dists[0]; int mini = 0;
    #pragma unroll
    for (int m = 1; m < NMODS; ++m)
        if (dists[m] < mind) { mind = dists[m]; mini = m; }

    // ---------------- cls: margin terms + top1 ----------------
    const float2* c2p = (const float2*)(cls + (size_t)r * NMODS);
    float cv[NMODS];
    #pragma unroll
    for (int i = 0; i < 3; ++i) { float2 c2 = c2p[i]; cv[2 * i] = c2.x; cv[2 * i + 1] = c2.y; }

    float clsmin = cv[0];
    #pragma unroll
    for (int m = 1; m < NMODS; ++m) clsmin = (m == mini) ? cv[m] : clsmin;

    float numcls_l = 0.f, summgn_l = 0.f;
    if (valid && (mind < 2.0f)) {
        #pragma unroll
        for (int m = 0; m < NMODS; ++m) {
            float mgn = clsmin - cv[m];
            if (((dists[m] - mind) > 0.2f) && (mgn < 0.2f)) {
                numcls_l += 1.0f;
                summgn_l += mgn;
            }
        }
    }

    float bc = cv[0]; int top1 = 0;
    #pragma unroll
    for (int m = 1; m < NMODS; ++m)
        if (cv[m] > bc) { bc = cv[m]; top1 = m; }

    float numreg_l = valid ? (float)__builtin_popcount(mask) : 0.f;

    // ---------------- main de / regloss loop: m outer, t inner ----------------
    float ade6x = 0.f, ade6y = 0.f, fde6x = 0.f, fde6y = 0.f;
    float ade1x = 0.f, ade1y = 0.f, fde1x = 0.f, fde1y = 0.f;
    float regloss = 0.f;

    const float4* r4 = (const float4*)rbase;
    #pragma unroll
    for (int m = 0; m < NMODS; ++m) {
        const float topf = (m == top1) ? 1.f : 0.f;
        const bool  best = (m == mini) && valid;
        #pragma unroll
        for (int q = 0; q < 15; ++q) {
            float4 v = r4[m * 15 + q];
            #pragma unroll
            for (int half = 0; half < 2; ++half) {
                const int t = 2 * q + half;
                const float rx = half ? v.z : v.x;
                const float ry = half ? v.w : v.y;
                float gxt = __low2float(gxy[t]),  gyt = __high2float(gxy[t]);
                float ct  = __low2float(ctst[t]), st  = __high2float(ctst[t]);
                float dx = fabsf(gxt - rx), dy = fabsf(gyt - ry);
                float ax = fabsf(ct * dx - st * dy);
                float ay = fabsf(st * dx + ct * dy);
                ade6x += ax; ade6y += ay;
                ade1x += topf * ax; ade1y += topf * ay;
                if (t == NPREDS - 1) {
                    fde6x += ax; fde6y += ay;
                    fde1x += topf * ax; fde1y += topf * ay;
                }
                if (best && ((mask >> t) & 1u)) {
                    float e0 = rx - gxt, e1 = ry - gyt;
                    float a0 = fabsf(e0), a1 = fabsf(e1);
                    regloss += (a0 < 1.f) ? (0.5f * e0 * e0) : (a0 - 0.5f);
                    regloss += (a1 < 1.f) ? (0.5f * e1 * e1) : (a1 - 0.5f);
                }
            }
        }
    }

    // ---------------- reduce: wave -> block -> atomic ----------------
    float vals[12] = { ade6x, ade6y, fde6x, fde6y, ade1x, ade1y, fde1x, fde1y,
                       regloss, summgn_l, numcls_l, numreg_l };
    #pragma unroll
    for (int i = 0; i < 12; ++i) vals[i] = wave_reduce(vals[i]);

    __shared__ float blk[4][12];
    const int lane = threadIdx.x & 63;
    const int wid  = threadIdx.x >> 6;
    if (lane == 0) {
        #pragma unroll
        for (int i = 0; i < 12; ++i) blk[wid][i] = vals[i];
    }
    __syncthreads();
    if (threadIdx.x < 12) {
        float s = blk[0][threadIdx.x] + blk[1][threadIdx.x]
                + blk[2][threadIdx.x] + blk[3][threadIdx.x];
        atomicAdd(&acc[threadIdx.x], s);
    }
}

__global__ void finalize(const float* __restrict__ acc, float* __restrict__ out) {
    if (threadIdx.x == 0) {
        float nc = acc[10], nr = acc[11];
        float cls_loss = 0.2f * nc - acc[9];
        float reg_loss = acc[8];
        float loss = cls_loss / (nc + 1e-10f) + reg_loss / (nr + 1e-10f);
        out[0]  = loss;
        out[1]  = cls_loss;
        out[2]  = nc;
        out[3]  = reg_loss;
        out[4]  = nr;
        out[5]  = acc[0];
        out[6]  = acc[1];
        out[7]  = acc[2];
        out[8]  = acc[3];
        out[9]  = 23592960.0f;   // 6*B*30
        out[10] = 786432.0f;     // 6*B
        out[11] = acc[4];
        out[12] = acc[5];
        out[13] = acc[6];
        out[14] = acc[7];
        out[15] = 3932160.0f;    // B*30
        out[16] = 131072.0f;     // B
    }
}

extern "C" void kernel_launch(void* const* d_in, const int* in_sizes, int n_in,
                              void* d_out, int out_size, void* d_ws, size_t ws_size,
                              hipStream_t stream) {
    const float* reg = (const float*)d_in[0];
    const float* cls = (const float*)d_in[1];
    const float* gt  = (const float*)d_in[2];
    const int*   has = (const int*)d_in[3];
    float* out = (float*)d_out;
    float* acc = (float*)d_ws;

    hipMemsetAsync(acc, 0, 12 * sizeof(float), stream);
    loss_lane<<<B_ROWS / 256, 256, 0, stream>>>(reg, cls, gt, has, acc);
    finalize<<<1, 64, 0, stream>>>(acc, out);
}

// Round 4
// 381.749 us; speedup vs baseline: 1.0812x; 1.0812x over previous
//
#include <hip/hip_runtime.h>
#include <math.h>

#define NROWS 131072
#define NMODS 6
#define NPREDS 30

// d_ws layout:
//   12 accumulator slots, 256 B apart (avoid same-cacheline atomic serialization)
//     0 ade6x, 1 ade6y, 2 fde6x, 3 fde6y, 4 ade1x, 5 ade1y, 6 fde1x, 7 fde1y,
//     8 regloss, 9 summgn, 10 numcls, 11 numreg
//   offset 4096:             state[NROWS*30] float4 {gx, gy, cos(-head), sin(-head)}
//   offset 4096 + 62914560:  meta[NROWS] uint2 {mask, mini | top1<<4 | valid<<8}

#define ACC_SLOT(ws, i) ((float*)((char*)(ws) + (size_t)(i) * 256))
#define STATE_OFF 4096
#define META_OFF  (4096 + (size_t)NROWS * NPREDS * 16)

__device__ __forceinline__ float wave_reduce(float v) {
    v += __shfl_xor(v, 32);
    v += __shfl_xor(v, 16);
    v += __shfl_xor(v, 8);
    v += __shfl_xor(v, 4);
    v += __shfl_xor(v, 2);
    v += __shfl_xor(v, 1);
    return v;
}

// ---------------- Kernel A: per-row state (thread-per-row, streaming) ----------------
__global__ __launch_bounds__(256) void row_state(
    const float* __restrict__ reg,   // [B,6,30,2]
    const float* __restrict__ cls,   // [B,6]
    const float* __restrict__ gt,    // [B,30,2]
    const int* __restrict__ has,     // [B,30] bool->int32
    float4* __restrict__ state,
    uint2* __restrict__ meta,
    void* ws)
{
    const int r = blockIdx.x * 256 + threadIdx.x;

    // ---- has -> bitmask ----
    const int2* h2 = (const int2*)(has + (size_t)r * NPREDS);
    unsigned mask = 0u;
    #pragma unroll
    for (int i = 0; i < 15; ++i) {
        int2 h = h2[i];
        mask |= (h.x != 0 ? 1u : 0u) << (2 * i);
        mask |= (h.y != 0 ? 1u : 0u) << (2 * i + 1);
    }
    const int  last_idx = mask ? (31 - __builtin_clz(mask)) : (NPREDS - 1);
    const bool valid    = (mask & ~1u) != 0u;

    // ---- moving ----
    const float4* g4 = (const float4*)(gt + (size_t)r * NPREDS * 2);
    const float2* g2 = (const float2*)(gt + (size_t)r * NPREDS * 2);
    float2 g29 = g2[NPREDS - 1];
    float4 cur = g4[0];
    float mdx = cur.x - g29.x, mdy = cur.y - g29.y;
    const bool moving = (mdx * mdx + mdy * mdy) > 4.0f;

    // ---- streaming heading + state writes (2 t's per float4) ----
    float4* st_out = state + (size_t)r * NPREDS;
    float seg_prev = 0.f;
    #pragma unroll
    for (int j = 0; j < 15; ++j) {
        float4 nxt = (j < 14) ? g4[j + 1] : cur;
        // t0 = 2j: point (cur.x,cur.y) -> (cur.z,cur.w)
        float seg0 = atan2f(cur.w - cur.y, cur.z - cur.x);     // seg[2j]
        float head0 = (j == 0) ? seg0
                    : ((seg0 == 0.f || seg_prev == 0.f) ? (seg0 + seg_prev)
                                                        : 0.5f * (seg0 + seg_prev));
        // t1 = 2j+1: point (cur.z,cur.w) -> (nxt.x,nxt.y)
        float head1;
        if (j < 14) {
            float seg1 = atan2f(nxt.y - cur.w, nxt.x - cur.z); // seg[2j+1]
            head1 = (seg1 == 0.f || seg0 == 0.f) ? (seg1 + seg0)
                                                 : 0.5f * (seg1 + seg0);
            seg_prev = seg1;
        } else {
            head1 = seg0;  // head[29] = seg[28]
        }
        if (!moving) { head0 = 0.f; head1 = 0.f; }
        float s0, c0, s1, c1;
        __sincosf(-head0, &s0, &c0);
        __sincosf(-head1, &s1, &c1);
        st_out[2 * j]     = make_float4(cur.x, cur.y, c0, s0);
        st_out[2 * j + 1] = make_float4(cur.z, cur.w, c1, s1);
        cur = nxt;
    }

    // ---- per-mode dist at last_idx -> mini ----
    float2 gl = g2[last_idx];
    const float2* rb = (const float2*)(reg + (size_t)r * NMODS * NPREDS * 2);
    float dists[NMODS];
    #pragma unroll
    for (int m = 0; m < NMODS; ++m) {
        float2 rl = rb[m * NPREDS + last_idx];
        float ax = rl.x - gl.x, ay = rl.y - gl.y;
        dists[m] = sqrtf(ax * ax + ay * ay);
    }
    float mind = dists[0]; int mini = 0;
    #pragma unroll
    for (int m = 1; m < NMODS; ++m)
        if (dists[m] < mind) { mind = dists[m]; mini = m; }

    // ---- cls margins + top1 ----
    const float2* c2 = (const float2*)(cls + (size_t)r * NMODS);
    float cv[NMODS];
    #pragma unroll
    for (int i = 0; i < 3; ++i) { float2 c = c2[i]; cv[2 * i] = c.x; cv[2 * i + 1] = c.y; }
    float clsmin = cv[0];
    #pragma unroll
    for (int m = 1; m < NMODS; ++m) clsmin = (m == mini) ? cv[m] : clsmin;

    float numcls_l = 0.f, summgn_l = 0.f;
    if (valid && (mind < 2.0f)) {
        #pragma unroll
        for (int m = 0; m < NMODS; ++m) {
            float mgn = clsmin - cv[m];
            if (((dists[m] - mind) > 0.2f) && (mgn < 0.2f)) {
                numcls_l += 1.0f;
                summgn_l += mgn;
            }
        }
    }
    float bc = cv[0]; int top1 = 0;
    #pragma unroll
    for (int m = 1; m < NMODS; ++m)
        if (cv[m] > bc) { bc = cv[m]; top1 = m; }

    float numreg_l = valid ? (float)__builtin_popcount(mask) : 0.f;

    meta[r] = make_uint2(mask, (unsigned)mini | ((unsigned)top1 << 4) | (valid ? 256u : 0u));

    // ---- reduce 3 scalars: wave -> block -> strided atomics ----
    float vals[3] = { summgn_l, numcls_l, numreg_l };
    #pragma unroll
    for (int i = 0; i < 3; ++i) vals[i] = wave_reduce(vals[i]);

    __shared__ float blk[4][3];
    const int lane = threadIdx.x & 63;
    const int wid  = threadIdx.x >> 6;
    if (lane == 0) {
        #pragma unroll
        for (int i = 0; i < 3; ++i) blk[wid][i] = vals[i];
    }
    __syncthreads();
    if (threadIdx.x < 3) {
        float s = blk[0][threadIdx.x] + blk[1][threadIdx.x]
                + blk[2][threadIdx.x] + blk[3][threadIdx.x];
        atomicAdd(ACC_SLOT(ws, 9 + threadIdx.x), s);
    }
}

// ---------------- Kernel B: coalesced de / regloss sweep ----------------
__global__ __launch_bounds__(256) void de_sweep(
    const float4* __restrict__ r4,       // reg as float4: [NROWS*90]
    const float4* __restrict__ state,
    const uint2* __restrict__ meta,
    void* ws)
{
    const int N4 = NROWS * 90;           // 11,796,480 float4s (2 elements each)
    float a6x = 0.f, a6y = 0.f, f6x = 0.f, f6y = 0.f;
    float a1x = 0.f, a1y = 0.f, f1x = 0.f, f1y = 0.f, rl = 0.f;

    for (int i = blockIdx.x * blockDim.x + threadIdx.x; i < N4;
         i += gridDim.x * blockDim.x) {
        float4 v = r4[i];
        // element pair (2i, 2i+1): same b and m always (30 even, pair even-aligned)
        unsigned b   = (unsigned)i / 90u;
        unsigned rem = (unsigned)i - b * 90u;
        unsigned m   = rem / 15u;
        unsigned t0  = (rem - m * 15u) * 2u;

        uint2 mt = meta[b];
        const float4* sp = state + (size_t)b * NPREDS + t0;
        float4 s0 = sp[0];
        float4 s1 = sp[1];

        unsigned mini = mt.y & 15u, top1 = (mt.y >> 4) & 15u;
        bool valid  = (mt.y & 256u) != 0u;
        bool isTop  = (m == top1);
        bool isBest = (m == mini) && valid;
        bool is29   = (t0 == 28u);       // second element is t=29

        // element 0 (t0)
        {
            float dx = fabsf(s0.x - v.x), dy = fabsf(s0.y - v.y);
            float ax = fabsf(s0.z * dx - s0.w * dy);
            float ay = fabsf(s0.w * dx + s0.z * dy);
            a6x += ax; a6y += ay;
            if (isTop) { a1x += ax; a1y += ay; }
            if (isBest && ((mt.x >> t0) & 1u)) {
                float e0 = v.x - s0.x, e1 = v.y - s0.y;
                float q0 = fabsf(e0), q1 = fabsf(e1);
                rl += (q0 < 1.f) ? (0.5f * e0 * e0) : (q0 - 0.5f);
                rl += (q1 < 1.f) ? (0.5f * e1 * e1) : (q1 - 0.5f);
            }
        }
        // element 1 (t0+1)
        {
            float dx = fabsf(s1.x - v.z), dy = fabsf(s1.y - v.w);
            float ax = fabsf(s1.z * dx - s1.w * dy);
            float ay = fabsf(s1.w * dx + s1.z * dy);
            a6x += ax; a6y += ay;
            if (isTop) { a1x += ax; a1y += ay; }
            if (is29) {
                f6x += ax; f6y += ay;
                if (isTop) { f1x += ax; f1y += ay; }
            }
            if (isBest && ((mt.x >> (t0 + 1u)) & 1u)) {
                float e0 = v.z - s1.x, e1 = v.w - s1.y;
                float q0 = fabsf(e0), q1 = fabsf(e1);
                rl += (q0 < 1.f) ? (0.5f * e0 * e0) : (q0 - 0.5f);
                rl += (q1 < 1.f) ? (0.5f * e1 * e1) : (q1 - 0.5f);
            }
        }
    }

    // ---- reduce 9 accumulators: wave -> block -> strided atomics ----
    float vals[9] = { a6x, a6y, f6x, f6y, a1x, a1y, f1x, f1y, rl };
    #pragma unroll
    for (int i = 0; i < 9; ++i) vals[i] = wave_reduce(vals[i]);

    __shared__ float blk[4][9];
    const int lane = threadIdx.x & 63;
    const int wid  = threadIdx.x >> 6;
    if (lane == 0) {
        #pragma unroll
        for (int i = 0; i < 9; ++i) blk[wid][i] = vals[i];
    }
    __syncthreads();
    if (threadIdx.x < 9) {
        float s = blk[0][threadIdx.x] + blk[1][threadIdx.x]
                + blk[2][threadIdx.x] + blk[3][threadIdx.x];
        atomicAdd(ACC_SLOT(ws, threadIdx.x), s);
    }
}

__global__ void finalize(void* ws, float* __restrict__ out) {
    if (threadIdx.x == 0) {
        float nc = *ACC_SLOT(ws, 10), nr = *ACC_SLOT(ws, 11);
        float cls_loss = 0.2f * nc - *ACC_SLOT(ws, 9);
        float reg_loss = *ACC_SLOT(ws, 8);
        float loss = cls_loss / (nc + 1e-10f) + reg_loss / (nr + 1e-10f);
        out[0]  = loss;
        out[1]  = cls_loss;
        out[2]  = nc;
        out[3]  = reg_loss;
        out[4]  = nr;
        out[5]  = *ACC_SLOT(ws, 0);
        out[6]  = *ACC_SLOT(ws, 1);
        out[7]  = *ACC_SLOT(ws, 2);
        out[8]  = *ACC_SLOT(ws, 3);
        out[9]  = 23592960.0f;   // 6*B*30
        out[10] = 786432.0f;     // 6*B
        out[11] = *ACC_SLOT(ws, 4);
        out[12] = *ACC_SLOT(ws, 5);
        out[13] = *ACC_SLOT(ws, 6);
        out[14] = *ACC_SLOT(ws, 7);
        out[15] = 3932160.0f;    // B*30
        out[16] = 131072.0f;     // B
    }
}

extern "C" void kernel_launch(void* const* d_in, const int* in_sizes, int n_in,
                              void* d_out, int out_size, void* d_ws, size_t ws_size,
                              hipStream_t stream) {
    const float* reg = (const float*)d_in[0];
    const float* cls = (const float*)d_in[1];
    const float* gt  = (const float*)d_in[2];
    const int*   has = (const int*)d_in[3];
    float* out = (float*)d_out;

    float4* state = (float4*)((char*)d_ws + STATE_OFF);
    uint2*  meta  = (uint2*)((char*)d_ws + META_OFF);

    hipMemsetAsync(d_ws, 0, 4096, stream);
    row_state<<<NROWS / 256, 256, 0, stream>>>(reg, cls, gt, has, state, meta, d_ws);
    de_sweep<<<2048, 256, 0, stream>>>((const float4*)reg, state, meta, d_ws);
    finalize<<<1, 64, 0, stream>>>(d_ws, out);
}

// Round 5
// 346.484 us; speedup vs baseline: 1.1912x; 1.1018x over previous
//
#include <hip/hip_runtime.h>
#include <math.h>

#define NROWS 131072
#define NMODS 6
#define NPREDS 30
#define RPB 16                    // rows per block
#define NBLK (NROWS / RPB)        // 8192
#define ELEMS (RPB * NMODS * 15)  // 1440 float4s per block (2 timesteps each)

// d_ws: 12 accumulator slots, 256 B apart:
// 0 ade6x, 1 ade6y, 2 fde6x, 3 fde6y, 4 ade1x, 5 ade1y, 6 fde1x, 7 fde1y,
// 8 regloss, 9 summgn, 10 numcls, 11 numreg
#define ACC_SLOT(ws, i) ((float*)((char*)(ws) + (size_t)(i) * 256))

__device__ __forceinline__ float wave_reduce(float v) {
    v += __shfl_xor(v, 32);
    v += __shfl_xor(v, 16);
    v += __shfl_xor(v, 8);
    v += __shfl_xor(v, 4);
    v += __shfl_xor(v, 2);
    v += __shfl_xor(v, 1);
    return v;
}

__global__ __launch_bounds__(256) void loss_fused(
    const float* __restrict__ reg,   // [B,6,30,2]
    const float* __restrict__ cls,   // [B,6]
    const float* __restrict__ gt,    // [B,30,2]
    const int* __restrict__ has,     // [B,30] bool->int32
    void* __restrict__ ws)
{
    const int tid = threadIdx.x;
    const int rb  = blockIdx.x * RPB;

    __shared__ float2 s_gt[RPB * NPREDS];   // 3840 B  {gx, gy} per (row,t)
    __shared__ float2 s_st[RPB * NPREDS];   // 3840 B  {cos(-head), sin(-head)}
    __shared__ uint2  s_meta[RPB];          // {mask, mini|top1<<4|valid<<8}
    __shared__ float  s_red[4][12];

    // ---- stage reg straight into registers, perfectly coalesced ----
    // thread tid owns flat float4 indices k = tid + 256*i within the block;
    // the same indices are processed in phase 3 — no LDS round trip for reg.
    const float4* reg4 = (const float4*)reg + (size_t)rb * 90;
    float4 rv[6];
    #pragma unroll
    for (int i = 0; i < 6; ++i) {
        int k = tid + i * 256;
        if (k < ELEMS) rv[i] = reg4[k];
    }

    // ---- stage gt into LDS (240 float4s, coalesced) ----
    if (tid < RPB * NPREDS / 2)
        ((float4*)s_gt)[tid] = ((const float4*)gt)[(size_t)rb * (NPREDS / 2) + tid];
    __syncthreads();

    float acc[12];
    #pragma unroll
    for (int i = 0; i < 12; ++i) acc[i] = 0.f;

    // ---- phase 2: per-row scalars (threads 0..15, one row each) ----
    if (tid < RPB) {
        const int r = rb + tid;
        const int2* h2 = (const int2*)(has + (size_t)r * NPREDS);
        unsigned mask = 0u;
        #pragma unroll
        for (int i = 0; i < 15; ++i) {
            int2 h = h2[i];
            mask |= (h.x != 0 ? 1u : 0u) << (2 * i);
            mask |= (h.y != 0 ? 1u : 0u) << (2 * i + 1);
        }
        const int  last  = mask ? (31 - __builtin_clz(mask)) : (NPREDS - 1);
        const bool valid = (mask & ~1u) != 0u;

        float2 gl = s_gt[tid * NPREDS + last];
        const float2* rrow = (const float2*)(reg + (size_t)r * NMODS * NPREDS * 2);
        float dists[NMODS];
        #pragma unroll
        for (int m = 0; m < NMODS; ++m) {
            float2 rl = rrow[m * NPREDS + last];
            float ax = rl.x - gl.x, ay = rl.y - gl.y;
            dists[m] = sqrtf(ax * ax + ay * ay);
        }
        float mind = dists[0]; int mini = 0;
        #pragma unroll
        for (int m = 1; m < NMODS; ++m)
            if (dists[m] < mind) { mind = dists[m]; mini = m; }

        const float2* c2 = (const float2*)(cls + (size_t)r * NMODS);
        float cv[NMODS];
        #pragma unroll
        for (int i = 0; i < 3; ++i) { float2 c = c2[i]; cv[2*i] = c.x; cv[2*i+1] = c.y; }
        float clsmin = cv[0];
        #pragma unroll
        for (int m = 1; m < NMODS; ++m) clsmin = (m == mini) ? cv[m] : clsmin;

        if (valid && (mind < 2.0f)) {
            #pragma unroll
            for (int m = 0; m < NMODS; ++m) {
                float mgn = clsmin - cv[m];
                if (((dists[m] - mind) > 0.2f) && (mgn < 0.2f)) {
                    acc[10] += 1.0f;   // numcls
                    acc[9]  += mgn;    // summgn
                }
            }
        }
        float bc = cv[0]; int top1 = 0;
        #pragma unroll
        for (int m = 1; m < NMODS; ++m)
            if (cv[m] > bc) { bc = cv[m]; top1 = m; }

        if (valid) acc[11] += (float)__builtin_popcount(mask);   // numreg

        s_meta[tid] = make_uint2(mask,
            (unsigned)mini | ((unsigned)top1 << 4) | (valid ? 256u : 0u));
    }

    // ---- phase 2b: headings -> s_st (all threads, 480 (row,t) pairs) ----
    #pragma unroll
    for (int it = 0; it < 2; ++it) {
        int idx = tid + it * 256;
        if (idx < RPB * NPREDS) {
            int row = idx / NPREDS;
            int t   = idx - row * NPREDS;
            const float2* g = s_gt + row * NPREDS;
            float2 g0 = g[0], g29 = g[NPREDS - 1];
            float mdx = g0.x - g29.x, mdy = g0.y - g29.y;
            bool moving = (mdx * mdx + mdy * mdy) > 4.0f;

            float2 cur = g[t];
            float2 prv = g[(t > 0) ? t - 1 : 0];
            float2 nxt = g[(t < NPREDS - 1) ? t + 1 : NPREDS - 1];
            float fwd = atan2f(nxt.y - cur.y, nxt.x - cur.x);  // 0 at t=29 (unused)
            float bwd = atan2f(cur.y - prv.y, cur.x - prv.x);  // 0 at t=0 (unused)
            float head = (t == 0) ? fwd
                       : ((t == NPREDS - 1) ? bwd
                       : ((fwd == 0.f || bwd == 0.f) ? (fwd + bwd)
                                                     : 0.5f * (fwd + bwd)));
            if (!moving) head = 0.f;
            float s, c;
            __sincosf(-head, &s, &c);
            s_st[idx] = make_float2(c, s);
        }
    }
    __syncthreads();

    // ---- phase 3: de / regloss sweep over register-held reg elements ----
    #pragma unroll
    for (int i = 0; i < 6; ++i) {
        int k = tid + i * 256;
        if (k < ELEMS) {
            int row = k / 90;
            int rem = k - row * 90;
            int m   = rem / 15;
            int q   = rem - m * 15;
            int t0  = 2 * q;

            uint2  mt  = s_meta[row];
            float4 gp  = ((const float4*)s_gt)[row * 15 + q];  // x0 y0 x1 y1
            float4 sp  = ((const float4*)s_st)[row * 15 + q];  // c0 s0 c1 s1
            float4 v   = rv[i];

            unsigned mini = mt.y & 15u, top1 = (mt.y >> 4) & 15u;
            bool valid  = (mt.y & 256u) != 0u;
            bool isTop  = ((unsigned)m == top1);
            bool isBest = ((unsigned)m == mini) && valid;
            bool is29   = (q == 14);

            // element 0 (t0)
            {
                float dx = fabsf(gp.x - v.x), dy = fabsf(gp.y - v.y);
                float ax = fabsf(sp.x * dx - sp.y * dy);
                float ay = fabsf(sp.y * dx + sp.x * dy);
                acc[0] += ax; acc[1] += ay;
                if (isTop) { acc[4] += ax; acc[5] += ay; }
                if (isBest && ((mt.x >> t0) & 1u)) {
                    float e0 = v.x - gp.x, e1 = v.y - gp.y;
                    float q0 = fabsf(e0), q1 = fabsf(e1);
                    acc[8] += (q0 < 1.f) ? (0.5f * e0 * e0) : (q0 - 0.5f);
                    acc[8] += (q1 < 1.f) ? (0.5f * e1 * e1) : (q1 - 0.5f);
                }
            }
            // element 1 (t0+1)
            {
                float dx = fabsf(gp.z - v.z), dy = fabsf(gp.w - v.w);
                float ax = fabsf(sp.z * dx - sp.w * dy);
                float ay = fabsf(sp.w * dx + sp.z * dy);
                acc[0] += ax; acc[1] += ay;
                if (isTop) { acc[4] += ax; acc[5] += ay; }
                if (is29) {
                    acc[2] += ax; acc[3] += ay;
                    if (isTop) { acc[6] += ax; acc[7] += ay; }
                }
                if (isBest && ((mt.x >> (t0 + 1)) & 1u)) {
                    float e0 = v.z - gp.z, e1 = v.w - gp.w;
                    float q0 = fabsf(e0), q1 = fabsf(e1);
                    acc[8] += (q0 < 1.f) ? (0.5f * e0 * e0) : (q0 - 0.5f);
                    acc[8] += (q1 < 1.f) ? (0.5f * e1 * e1) : (q1 - 0.5f);
                }
            }
        }
    }

    // ---- reduce: wave -> block -> strided atomics ----
    #pragma unroll
    for (int i = 0; i < 12; ++i) acc[i] = wave_reduce(acc[i]);

    const int lane = tid & 63;
    const int wid  = tid >> 6;
    if (lane == 0) {
        #pragma unroll
        for (int i = 0; i < 12; ++i) s_red[wid][i] = acc[i];
    }
    __syncthreads();
    if (tid < 12) {
        float s = s_red[0][tid] + s_red[1][tid] + s_red[2][tid] + s_red[3][tid];
        atomicAdd(ACC_SLOT(ws, tid), s);
    }
}

__global__ void finalize(void* ws, float* __restrict__ out) {
    if (threadIdx.x == 0) {
        float nc = *ACC_SLOT(ws, 10), nr = *ACC_SLOT(ws, 11);
        float cls_loss = 0.2f * nc - *ACC_SLOT(ws, 9);
        float reg_loss = *ACC_SLOT(ws, 8);
        float loss = cls_loss / (nc + 1e-10f) + reg_loss / (nr + 1e-10f);
        out[0]  = loss;
        out[1]  = cls_loss;
        out[2]  = nc;
        out[3]  = reg_loss;
        out[4]  = nr;
        out[5]  = *ACC_SLOT(ws, 0);
        out[6]  = *ACC_SLOT(ws, 1);
        out[7]  = *ACC_SLOT(ws, 2);
        out[8]  = *ACC_SLOT(ws, 3);
        out[9]  = 23592960.0f;   // 6*B*30
        out[10] = 786432.0f;     // 6*B
        out[11] = *ACC_SLOT(ws, 4);
        out[12] = *ACC_SLOT(ws, 5);
        out[13] = *ACC_SLOT(ws, 6);
        out[14] = *ACC_SLOT(ws, 7);
        out[15] = 3932160.0f;    // B*30
        out[16] = 131072.0f;     // B
    }
}

extern "C" void kernel_launch(void* const* d_in, const int* in_sizes, int n_in,
                              void* d_out, int out_size, void* d_ws, size_t ws_size,
                              hipStream_t stream) {
    const float* reg = (const float*)d_in[0];
    const float* cls = (const float*)d_in[1];
    const float* gt  = (const float*)d_in[2];
    const int*   has = (const int*)d_in[3];
    float* out = (float*)d_out;

    hipMemsetAsync(d_ws, 0, 4096, stream);
    loss_fused<<<NBLK, 256, 0, stream>>>(reg, cls, gt, has, d_ws);
    finalize<<<1, 64, 0, stream>>>(d_ws, out);
}

// Round 6
// 328.847 us; speedup vs baseline: 1.2551x; 1.0536x over previous
//
#include <hip/hip_runtime.h>
#include <math.h>

#define NROWS 131072
#define NMODS 6
#define NPREDS 30
#define RPG 4                      // rows per group (one wave iteration)
#define NGROUPS (NROWS / RPG)      // 32768
#define NBLK 2048
#define NWAVES (NBLK * 4)          // 8192 -> 4 groups per wave
#define GF4 (RPG * NMODS * 15)     // 360 reg float4s per group

// d_ws: 12 accumulator slots, 256 B apart:
// 0 ade6x, 1 ade6y, 2 fde6x, 3 fde6y, 4 ade1x, 5 ade1y, 6 fde1x, 7 fde1y,
// 8 regloss, 9 summgn, 10 numcls, 11 numreg
#define ACC_SLOT(ws, i) ((float*)((char*)(ws) + (size_t)(i) * 256))

// s_waitcnt lgkmcnt(0) ONLY (vmcnt=63, expcnt=7 untouched) — does not drain
// the in-flight reg prefetch loads.
#define LGKM_WAIT() do { \
    __builtin_amdgcn_wave_barrier(); \
    __builtin_amdgcn_s_waitcnt(0xC07F); \
    __builtin_amdgcn_wave_barrier(); \
} while (0)

__device__ __forceinline__ float wave_reduce(float v) {
    v += __shfl_xor(v, 32);
    v += __shfl_xor(v, 16);
    v += __shfl_xor(v, 8);
    v += __shfl_xor(v, 4);
    v += __shfl_xor(v, 2);
    v += __shfl_xor(v, 1);
    return v;
}

__global__ __launch_bounds__(256) void loss_wave(
    const float* __restrict__ reg,   // [B,6,30,2]
    const float* __restrict__ cls,   // [B,6]
    const float* __restrict__ gt,    // [B,30,2]
    const int* __restrict__ has,     // [B,30] bool->int32
    void* __restrict__ ws)
{
    const int tid  = threadIdx.x;
    const int lane = tid & 63;
    const int wid  = tid >> 6;
    const int gwave = blockIdx.x * 4 + wid;

    // wave-private LDS (no cross-wave sharing -> no __syncthreads needed)
    __shared__ float2 s_gt[4][RPG * NPREDS];   // [wave][120] {gx,gy}
    __shared__ float2 s_ct[4][RPG * NPREDS];   // [wave][120] {cos(-h),sin(-h)}
    __shared__ float  s_red[4][12];

    float acc[12];
    #pragma unroll
    for (int i = 0; i < 12; ++i) acc[i] = 0.f;

    for (int g = gwave; g < NGROUPS; g += NWAVES) {
        const int rb = g * RPG;

        // ---- issue gt/has first, then reg: the gt-staging vmcnt wait
        //      leaves the 6 reg loads in flight until phase 3 ----
        float4 gv = make_float4(0.f, 0.f, 0.f, 0.f);
        if (lane < 60) gv = ((const float4*)gt)[(size_t)rb * 15 + lane];
        int2 hv = make_int2(0, 0);
        if (lane < 60) hv = ((const int2*)has)[(size_t)rb * 15 + lane];

        const float4* reg4 = (const float4*)reg + (size_t)rb * 90;
        float4 rv[6];
        #pragma unroll
        for (int i = 0; i < 5; ++i) rv[i] = reg4[lane + 64 * i];
        if (lane < 40) rv[5] = reg4[lane + 320];

        // ---- has bits: lane l<60 holds t=2*(l%15),2*(l%15)+1 of row l/15 ----
        unsigned long long bx = __ballot(lane < 60 && hv.x != 0);
        unsigned long long by = __ballot(lane < 60 && hv.y != 0);

        // ---- stage gt into wave-private LDS ----
        if (lane < 60) ((float4*)s_gt[wid])[lane] = gv;
        LGKM_WAIT();

        // ---- headings: 120 (row,t) pairs, 2 sweeps ----
        #pragma unroll
        for (int it = 0; it < 2; ++it) {
            int idx = lane + it * 64;
            if (idx < RPG * NPREDS) {
                int row = idx / NPREDS;
                int t   = idx - row * NPREDS;
                const float2* gp = s_gt[wid] + row * NPREDS;
                float2 g0 = gp[0], g29 = gp[NPREDS - 1];
                float mdx = g0.x - g29.x, mdy = g0.y - g29.y;
                bool moving = (mdx * mdx + mdy * mdy) > 4.0f;

                float2 cur = gp[t];
                float2 prv = gp[(t > 0) ? t - 1 : 0];
                float2 nxt = gp[(t < NPREDS - 1) ? t + 1 : NPREDS - 1];
                float fwd = atan2f(nxt.y - cur.y, nxt.x - cur.x);
                float bwd = atan2f(cur.y - prv.y, cur.x - prv.x);
                float head = (t == 0) ? fwd
                           : ((t == NPREDS - 1) ? bwd
                           : ((fwd == 0.f || bwd == 0.f) ? (fwd + bwd)
                                                         : 0.5f * (fwd + bwd)));
                if (!moving) head = 0.f;
                float s, c;
                __sincosf(-head, &s, &c);
                s_ct[wid][idx] = make_float2(c, s);
            }
        }

        // ---- per-row scalars on lanes 0..3 (row = lane) ----
        unsigned metaval = 0u;
        if (lane < RPG) {
            unsigned ex = (unsigned)((bx >> (15 * lane)) & 0x7FFFull);
            unsigned ey = (unsigned)((by >> (15 * lane)) & 0x7FFFull);
            int le = ex ? 2 * (31 - __builtin_clz(ex)) : -1;
            int lo = ey ? 2 * (31 - __builtin_clz(ey)) + 1 : -1;
            int last = (le > lo) ? le : lo;
            if (last < 0) last = NPREDS - 1;
            bool valid = ((ex & ~1u) | ey) != 0u;

            float2 gl = s_gt[wid][lane * NPREDS + last];
            const float2* rr = (const float2*)reg + (size_t)(rb + lane) * 180;
            float dists[NMODS];
            #pragma unroll
            for (int m = 0; m < NMODS; ++m) {
                float2 rl = rr[m * NPREDS + last];
                float ax = rl.x - gl.x, ay = rl.y - gl.y;
                dists[m] = sqrtf(ax * ax + ay * ay);
            }
            float mind = dists[0]; int mini = 0;
            #pragma unroll
            for (int m = 1; m < NMODS; ++m)
                if (dists[m] < mind) { mind = dists[m]; mini = m; }

            const float2* cc = (const float2*)cls + (size_t)(rb + lane) * 3;
            float cv[NMODS];
            #pragma unroll
            for (int i = 0; i < 3; ++i) { float2 c = cc[i]; cv[2*i] = c.x; cv[2*i+1] = c.y; }
            float clsmin = cv[0];
            #pragma unroll
            for (int m = 1; m < NMODS; ++m) clsmin = (m == mini) ? cv[m] : clsmin;

            if (valid && (mind < 2.0f)) {
                #pragma unroll
                for (int m = 0; m < NMODS; ++m) {
                    float mgn = clsmin - cv[m];
                    if (((dists[m] - mind) > 0.2f) && (mgn < 0.2f)) {
                        acc[10] += 1.0f;   // numcls
                        acc[9]  += mgn;    // summgn
                    }
                }
            }
            float bc = cv[0]; int top1 = 0;
            #pragma unroll
            for (int m = 1; m < NMODS; ++m)
                if (cv[m] > bc) { bc = cv[m]; top1 = m; }

            if (valid)
                acc[11] += (float)(__builtin_popcount(ex) + __builtin_popcount(ey));

            metaval = (unsigned)mini | ((unsigned)top1 << 4) | (valid ? 256u : 0u);
        }
        LGKM_WAIT();   // s_ct writes visible before phase-3 reads

        // ---- phase 3: de / regloss sweep over register-held reg ----
        #pragma unroll
        for (int i = 0; i < 6; ++i) {
            int k = lane + 64 * i;
            bool act = (i < 5) || (lane < 40);
            int kk = act ? k : 0;
            int row = kk / 90;
            int rem = kk - row * 90;
            int m   = rem / 15;
            int q   = rem - 15 * m;
            int t0  = 2 * q;

            unsigned mv = (unsigned)__shfl((int)metaval, row);
            unsigned ex = (unsigned)((bx >> (15 * row)) & 0x7FFFull);
            unsigned ey = (unsigned)((by >> (15 * row)) & 0x7FFFull);
            float4 gp = ((const float4*)s_gt[wid])[row * 15 + q];  // x0 y0 x1 y1
            float4 sp = ((const float4*)s_ct[wid])[row * 15 + q];  // c0 s0 c1 s1
            float4 v  = rv[i];

            unsigned mini = mv & 15u, top1 = (mv >> 4) & 15u;
            bool valid  = (mv & 256u) != 0u;
            bool isTop  = ((unsigned)m == top1);
            bool isBest = ((unsigned)m == mini) && valid;

            if (act) {
                // element 0 (t = t0)
                {
                    float dx = fabsf(gp.x - v.x), dy = fabsf(gp.y - v.y);
                    float ax = fabsf(sp.x * dx - sp.y * dy);
                    float ay = fabsf(sp.y * dx + sp.x * dy);
                    acc[0] += ax; acc[1] += ay;
                    if (isTop) { acc[4] += ax; acc[5] += ay; }
                    if (isBest && ((ex >> q) & 1u)) {
                        float e0 = v.x - gp.x, e1 = v.y - gp.y;
                        float q0 = fabsf(e0), q1 = fabsf(e1);
                        acc[8] += (q0 < 1.f) ? (0.5f * e0 * e0) : (q0 - 0.5f);
                        acc[8] += (q1 < 1.f) ? (0.5f * e1 * e1) : (q1 - 0.5f);
                    }
                }
                // element 1 (t = t0+1)
                {
                    float dx = fabsf(gp.z - v.z), dy = fabsf(gp.w - v.w);
                    float ax = fabsf(sp.z * dx - sp.w * dy);
                    float ay = fabsf(sp.w * dx + sp.z * dy);
                    acc[0] += ax; acc[1] += ay;
                    if (isTop) { acc[4] += ax; acc[5] += ay; }
                    if (q == 14) {                       // t = 29
                        acc[2] += ax; acc[3] += ay;
                        if (isTop) { acc[6] += ax; acc[7] += ay; }
                    }
                    if (isBest && ((ey >> q) & 1u)) {
                        float e0 = v.z - gp.z, e1 = v.w - gp.w;
                        float q0 = fabsf(e0), q1 = fabsf(e1);
                        acc[8] += (q0 < 1.f) ? (0.5f * e0 * e0) : (q0 - 0.5f);
                        acc[8] += (q1 < 1.f) ? (0.5f * e1 * e1) : (q1 - 0.5f);
                    }
                }
            }
        }
        __builtin_amdgcn_wave_barrier();  // keep next iter's ds_writes after our reads
    }

    // ---- reduce: wave -> block -> strided atomics ----
    #pragma unroll
    for (int i = 0; i < 12; ++i) acc[i] = wave_reduce(acc[i]);

    if (lane == 0) {
        #pragma unroll
        for (int i = 0; i < 12; ++i) s_red[wid][i] = acc[i];
    }
    __syncthreads();
    if (tid < 12) {
        float s = s_red[0][tid] + s_red[1][tid] + s_red[2][tid] + s_red[3][tid];
        atomicAdd(ACC_SLOT(ws, tid), s);
    }
}

__global__ void finalize(void* ws, float* __restrict__ out) {
    if (threadIdx.x == 0) {
        float nc = *ACC_SLOT(ws, 10), nr = *ACC_SLOT(ws, 11);
        float cls_loss = 0.2f * nc - *ACC_SLOT(ws, 9);
        float reg_loss = *ACC_SLOT(ws, 8);
        float loss = cls_loss / (nc + 1e-10f) + reg_loss / (nr + 1e-10f);
        out[0]  = loss;
        out[1]  = cls_loss;
        out[2]  = nc;
        out[3]  = reg_loss;
        out[4]  = nr;
        out[5]  = *ACC_SLOT(ws, 0);
        out[6]  = *ACC_SLOT(ws, 1);
        out[7]  = *ACC_SLOT(ws, 2);
        out[8]  = *ACC_SLOT(ws, 3);
        out[9]  = 23592960.0f;   // 6*B*30
        out[10] = 786432.0f;     // 6*B
        out[11] = *ACC_SLOT(ws, 4);
        out[12] = *ACC_SLOT(ws, 5);
        out[13] = *ACC_SLOT(ws, 6);
        out[14] = *ACC_SLOT(ws, 7);
        out[15] = 3932160.0f;    // B*30
        out[16] = 131072.0f;     // B
    }
}

extern "C" void kernel_launch(void* const* d_in, const int* in_sizes, int n_in,
                              void* d_out, int out_size, void* d_ws, size_t ws_size,
                              hipStream_t stream) {
    const float* reg = (const float*)d_in[0];
    const float* cls = (const float*)d_in[1];
    const float* gt  = (const float*)d_in[2];
    const int*   has = (const int*)d_in[3];
    float* out = (float*)d_out;

    hipMemsetAsync(d_ws, 0, 4096, stream);
    loss_wave<<<NBLK, 256, 0, stream>>>(reg, cls, gt, has, d_ws);
    finalize<<<1, 64, 0, stream>>>(d_ws, out);
}

// Round 7
// 304.503 us; speedup vs baseline: 1.3555x; 1.0799x over previous
//
#include <hip/hip_runtime.h>
#include <math.h>

#define NROWS 131072
#define NMODS 6
#define NPREDS 30
#define RPG 4                      // rows per group (one wave iteration)
#define NGROUPS (NROWS / RPG)      // 32768
#define NBLK 2048
#define NWAVES (NBLK * 4)          // 8192 -> 4 groups per wave

// d_ws: 12 accumulator slots, 256 B apart:
// 0 ade6x, 1 ade6y, 2 fde6x, 3 fde6y, 4 ade1x, 5 ade1y, 6 fde1x, 7 fde1y,
// 8 regloss, 9 summgn, 10 numcls, 11 numreg
#define ACC_SLOT(ws, i) ((float*)((char*)(ws) + (size_t)(i) * 256))

// s_waitcnt lgkmcnt(0) ONLY (vmcnt=63, expcnt=7 untouched) — does not drain
// in-flight global loads.
#define LGKM_WAIT() do { \
    __builtin_amdgcn_wave_barrier(); \
    __builtin_amdgcn_s_waitcnt(0xC07F); \
    __builtin_amdgcn_wave_barrier(); \
} while (0)

__device__ __forceinline__ float wave_reduce(float v) {
    v += __shfl_xor(v, 32);
    v += __shfl_xor(v, 16);
    v += __shfl_xor(v, 8);
    v += __shfl_xor(v, 4);
    v += __shfl_xor(v, 2);
    v += __shfl_xor(v, 1);
    return v;
}

__global__ __launch_bounds__(256) void loss_wave(
    const float* __restrict__ reg,   // [B,6,30,2]
    const float* __restrict__ cls,   // [B,6]
    const float* __restrict__ gt,    // [B,30,2]
    const int* __restrict__ has,     // [B,30] bool->int32
    void* __restrict__ ws)
{
    const int tid   = threadIdx.x;
    const int lane  = tid & 63;
    const int wid   = tid >> 6;
    const int gwave = blockIdx.x * 4 + wid;

    // wave-private LDS tiles (no __syncthreads in hot loop)
    __shared__ float4 s_gt[4][RPG * 15];   // {x0,y0,x1,y1} per (row, q)
    __shared__ float4 s_ct[4][RPG * 15];   // {c0,s0,c1,s1} per (row, q)
    __shared__ float  s_red[4][12];

    const int row = lane / 15;             // staging row (valid lane<60)
    const int q   = lane - row * 15;       // timestep pair index

    float acc[12];
    #pragma unroll
    for (int i = 0; i < 12; ++i) acc[i] = 0.f;

    for (int g = gwave; g < NGROUPS; g += NWAVES) {
        const int rb = g * RPG;

        // ---- issue gt/has, then bulk reg: later vmcnt waits for gt/has
        //      leave the 6 reg loads in flight until phase 3 ----
        float4 gv = make_float4(0.f, 0.f, 0.f, 0.f);
        int2   hv = make_int2(0, 0);
        if (lane < 60) {
            gv = ((const float4*)gt)[(size_t)rb * 15 + lane];
            hv = ((const int2*)has)[(size_t)rb * 15 + lane];
        }
        const float4* reg4 = (const float4*)reg + (size_t)rb * 90;
        float4 rv[6];
        #pragma unroll
        for (int i = 0; i < 5; ++i) rv[i] = reg4[lane + 64 * i];
        if (lane < 40) rv[5] = reg4[lane + 320];

        // ---- has bits ----
        unsigned long long bx = __ballot(lane < 60 && hv.x != 0);
        unsigned long long by = __ballot(lane < 60 && hv.y != 0);

        // ---- per-row (lanes 0..3): last idx + issue scattered loads early ----
        unsigned ex = 0u, ey = 0u;
        int last = NPREDS - 1;
        bool valid = false;
        float2 rl[NMODS];
        float2 cc[3];
        if (lane < RPG) {
            ex = (unsigned)((bx >> (15 * lane)) & 0x7FFFull);
            ey = (unsigned)((by >> (15 * lane)) & 0x7FFFull);
            int le = ex ? 2 * (31 - __builtin_clz(ex)) : -1;
            int lo = ey ? 2 * (31 - __builtin_clz(ey)) + 1 : -1;
            last = (le > lo) ? le : lo;
            if (last < 0) last = NPREDS - 1;
            valid = ((ex & ~1u) | ey) != 0u;

            const float2* rr = (const float2*)reg + (size_t)(rb + lane) * 180;
            #pragma unroll
            for (int m = 0; m < NMODS; ++m) rl[m] = rr[m * NPREDS + last];
            const float2* cp = (const float2*)cls + (size_t)(rb + lane) * 3;
            #pragma unroll
            for (int i = 0; i < 3; ++i) cc[i] = cp[i];
        }

        // ---- headings fully in registers: seg once per segment ----
        // seg[2q] in-lane; seg[2q+1] needs next lane's (x0,y0)
        float seg_e = atan2f(gv.w - gv.y, gv.z - gv.x);          // seg[2q]
        float nx = __shfl(gv.x, lane + 1);
        float ny = __shfl(gv.y, lane + 1);
        float seg_o = atan2f(ny - gv.w, nx - gv.z);              // seg[2q+1] (q<14)
        float so_p  = __shfl(seg_o, lane - 1);                   // seg[2q-1] (q>0)

        const int base = row * 15;
        float g0x  = __shfl(gv.x, base),      g0y  = __shfl(gv.y, base);
        float g29x = __shfl(gv.z, base + 14), g29y = __shfl(gv.w, base + 14);
        float mdx = g0x - g29x, mdy = g0y - g29y;
        const bool moving = (mdx * mdx + mdy * mdy) > 4.0f;

        float head0 = (q == 0) ? seg_e
                    : ((seg_e == 0.f || so_p == 0.f) ? (seg_e + so_p)
                                                     : 0.5f * (seg_e + so_p));
        float head1 = (q == 14) ? seg_e
                    : ((seg_o == 0.f || seg_e == 0.f) ? (seg_o + seg_e)
                                                      : 0.5f * (seg_o + seg_e));
        if (!moving) { head0 = 0.f; head1 = 0.f; }
        float c0, s0, c1, s1;
        __sincosf(-head0, &s0, &c0);
        __sincosf(-head1, &s1, &c1);

        if (lane < 60) {
            s_gt[wid][lane] = gv;
            s_ct[wid][lane] = make_float4(c0, s0, c1, s1);
        }
        LGKM_WAIT();   // single LDS turnaround per group

        // ---- per-row scalars (lanes 0..3), loads already in flight ----
        unsigned metaval = 0u;
        if (lane < RPG) {
            float4 gq = s_gt[wid][lane * 15 + (last >> 1)];
            float glx = (last & 1) ? gq.z : gq.x;
            float gly = (last & 1) ? gq.w : gq.y;

            float dists[NMODS];
            #pragma unroll
            for (int m = 0; m < NMODS; ++m) {
                float ax = rl[m].x - glx, ay = rl[m].y - gly;
                dists[m] = sqrtf(ax * ax + ay * ay);
            }
            float mind = dists[0]; int mini = 0;
            #pragma unroll
            for (int m = 1; m < NMODS; ++m)
                if (dists[m] < mind) { mind = dists[m]; mini = m; }

            float cv[NMODS];
            #pragma unroll
            for (int i = 0; i < 3; ++i) { cv[2*i] = cc[i].x; cv[2*i+1] = cc[i].y; }
            float clsmin = cv[0];
            #pragma unroll
            for (int m = 1; m < NMODS; ++m) clsmin = (m == mini) ? cv[m] : clsmin;

            if (valid && (mind < 2.0f)) {
                #pragma unroll
                for (int m = 0; m < NMODS; ++m) {
                    float mgn = clsmin - cv[m];
                    if (((dists[m] - mind) > 0.2f) && (mgn < 0.2f)) {
                        acc[10] += 1.0f;   // numcls
                        acc[9]  += mgn;    // summgn
                    }
                }
            }
            float bc = cv[0]; int top1 = 0;
            #pragma unroll
            for (int m = 1; m < NMODS; ++m)
                if (cv[m] > bc) { bc = cv[m]; top1 = m; }

            if (valid)
                acc[11] += (float)(__builtin_popcount(ex) + __builtin_popcount(ey));

            metaval = (unsigned)mini | ((unsigned)top1 << 4) | (valid ? 256u : 0u);
        }

        // ---- phase 3: de / regloss sweep over register-held reg ----
        #pragma unroll
        for (int i = 0; i < 6; ++i) {
            int k = lane + 64 * i;
            bool act = (i < 5) || (lane < 40);
            int kk = act ? k : 0;
            int rw  = kk / 90;
            int rem = kk - rw * 90;
            int m   = rem / 15;
            int qq  = rem - 15 * m;

            unsigned mv  = (unsigned)__shfl((int)metaval, rw);
            unsigned exr = (unsigned)((bx >> (15 * rw)) & 0x7FFFull);
            unsigned eyr = (unsigned)((by >> (15 * rw)) & 0x7FFFull);
            float4 gp = s_gt[wid][rw * 15 + qq];   // x0 y0 x1 y1
            float4 sp = s_ct[wid][rw * 15 + qq];   // c0 s0 c1 s1
            float4 v  = rv[i];

            unsigned mini = mv & 15u, top1 = (mv >> 4) & 15u;
            bool vld    = (mv & 256u) != 0u;
            bool isTop  = ((unsigned)m == top1);
            bool isBest = ((unsigned)m == mini) && vld;

            if (act) {
                // element 0 (t = 2qq)
                {
                    float dx = fabsf(gp.x - v.x), dy = fabsf(gp.y - v.y);
                    float ax = fabsf(sp.x * dx - sp.y * dy);
                    float ay = fabsf(sp.y * dx + sp.x * dy);
                    acc[0] += ax; acc[1] += ay;
                    if (isTop) { acc[4] += ax; acc[5] += ay; }
                    if (isBest && ((exr >> qq) & 1u)) {
                        float e0 = v.x - gp.x, e1 = v.y - gp.y;
                        float q0 = fabsf(e0), q1 = fabsf(e1);
                        acc[8] += (q0 < 1.f) ? (0.5f * e0 * e0) : (q0 - 0.5f);
                        acc[8] += (q1 < 1.f) ? (0.5f * e1 * e1) : (q1 - 0.5f);
                    }
                }
                // element 1 (t = 2qq+1)
                {
                    float dx = fabsf(gp.z - v.z), dy = fabsf(gp.w - v.w);
                    float ax = fabsf(sp.z * dx - sp.w * dy);
                    float ay = fabsf(sp.w * dx + sp.z * dy);
                    acc[0] += ax; acc[1] += ay;
                    if (isTop) { acc[4] += ax; acc[5] += ay; }
                    if (qq == 14) {                      // t = 29
                        acc[2] += ax; acc[3] += ay;
                        if (isTop) { acc[6] += ax; acc[7] += ay; }
                    }
                    if (isBest && ((eyr >> qq) & 1u)) {
                        float e0 = v.z - gp.z, e1 = v.w - gp.w;
                        float q0 = fabsf(e0), q1 = fabsf(e1);
                        acc[8] += (q0 < 1.f) ? (0.5f * e0 * e0) : (q0 - 0.5f);
                        acc[8] += (q1 < 1.f) ? (0.5f * e1 * e1) : (q1 - 0.5f);
                    }
                }
            }
        }
        __builtin_amdgcn_wave_barrier();  // keep next iter's ds_writes ordered after reads
    }

    // ---- reduce: wave -> block -> strided atomics ----
    #pragma unroll
    for (int i = 0; i < 12; ++i) acc[i] = wave_reduce(acc[i]);

    if (lane == 0) {
        #pragma unroll
        for (int i = 0; i < 12; ++i) s_red[wid][i] = acc[i];
    }
    __syncthreads();
    if (tid < 12) {
        float s = s_red[0][tid] + s_red[1][tid] + s_red[2][tid] + s_red[3][tid];
        atomicAdd(ACC_SLOT(ws, tid), s);
    }
}

__global__ void finalize(void* ws, float* __restrict__ out) {
    if (threadIdx.x == 0) {
        float nc = *ACC_SLOT(ws, 10), nr = *ACC_SLOT(ws, 11);
        float cls_loss = 0.2f * nc - *ACC_SLOT(ws, 9);
        float reg_loss = *ACC_SLOT(ws, 8);
        float loss = cls_loss / (nc + 1e-10f) + reg_loss / (nr + 1e-10f);
        out[0]  = loss;
        out[1]  = cls_loss;
        out[2]  = nc;
        out[3]  = reg_loss;
        out[4]  = nr;
        out[5]  = *ACC_SLOT(ws, 0);
        out[6]  = *ACC_SLOT(ws, 1);
        out[7]  = *ACC_SLOT(ws, 2);
        out[8]  = *ACC_SLOT(ws, 3);
        out[9]  = 23592960.0f;   // 6*B*30
        out[10] = 786432.0f;     // 6*B
        out[11] = *ACC_SLOT(ws, 4);
        out[12] = *ACC_SLOT(ws, 5);
        out[13] = *ACC_SLOT(ws, 6);
        out[14] = *ACC_SLOT(ws, 7);
        out[15] = 3932160.0f;    // B*30
        out[16] = 131072.0f;     // B
    }
}

extern "C" void kernel_launch(void* const* d_in, const int* in_sizes, int n_in,
                              void* d_out, int out_size, void* d_ws, size_t ws_size,
                              hipStream_t stream) {
    const float* reg = (const float*)d_in[0];
    const float* cls = (const float*)d_in[1];
    const float* gt  = (const float*)d_in[2];
    const int*   has = (const int*)d_in[3];
    float* out = (float*)d_out;

    hipMemsetAsync(d_ws, 0, 4096, stream);
    loss_wave<<<NBLK, 256, 0, stream>>>(reg, cls, gt, has, d_ws);
    finalize<<<1, 64, 0, stream>>>(d_ws, out);
}